// Round 9
// baseline (77.199 us; speedup 1.0000x reference)
//
#include <hip/hip_runtime.h>
#include <hip/hip_bf16.h>
#include <stdint.h>

typedef __bf16 bf16x8 __attribute__((ext_vector_type(8)));
typedef float  f32x4  __attribute__((ext_vector_type(4)));
typedef unsigned short u16x8 __attribute__((ext_vector_type(8)));

#define NB 32
#define NC 128
#define NH 56
#define NW 56
#define NK 4
#define NCO 128
#define NCR 32
#define NHW 3136
#define TEMPER 30.0f

// ws byte offsets
#define WS_ATTN   0u         // 512 B
#define WS_BC     4096u      // 16 KB
#define WS_ROWSUM 65536u     // f32 [32][58][128] = 950,272 B
#define WS_WC     1048576u   // bf16 [32][9][128][128] = 9,437,184 B
#define WS_XT     10485760u  // bf16 [32][58][58][128] = 27,557,888 B

// fp32 NCHW -> bf16 [b][hp=58][wp=58][c=128] with zero halo, via LDS transpose.
// XCD-aligned to conv's b-map. Emits rowsum (pool fused).
__global__ void xt_kernel(const float* __restrict__ x, __hip_bfloat16* __restrict__ xt,
                          float* __restrict__ rowsum) {
  __shared__ float lds[58 * 133];
  int xcd = blockIdx.x & 7;
  int j   = blockIdx.x >> 3;               // 0..231
  int b   = xcd * 4 + j / 58;
  int hp  = j % 58;
  int blk = b * 58 + hp;
  int h = hp - 1;
  bool hin = (h >= 0) && (h < NH);
  int tid = threadIdx.x;
  if (hin) {
    const float* xrow = x + ((size_t)b * NC) * NHW + (size_t)h * NW;
    for (int i = tid; i < 128 * 14; i += 256) {
      int c = i / 14;
      int w4 = (i - c * 14) * 4;
      float4 v = *(const float4*)(xrow + (size_t)c * NHW + w4);
      int base = (w4 + 1) * 133 + c;
      lds[base]         = v.x;
      lds[base + 133]   = v.y;
      lds[base + 2*133] = v.z;
      lds[base + 3*133] = v.w;
    }
  }
  __syncthreads();
  __hip_bfloat16* orow = xt + (size_t)blk * (58 * 128);
  for (int i = tid; i < 58 * 16; i += 256) {
    int wp = i >> 4;
    int cg = (i & 15) << 3;
    u16x8 o;
    if (!hin || wp == 0 || wp == 57) {
      o = (u16x8)0;
    } else {
      const float* src = lds + wp * 133 + cg;
      #pragma unroll
      for (int jx = 0; jx < 8; ++jx) {
        union { __hip_bfloat16 b; unsigned short u; } cv;
        cv.b = __float2bfloat16(src[jx]);
        o[jx] = cv.u;
      }
    }
    *(u16x8*)(orow + wp * 128 + cg) = o;
  }
  if (hin && tid < 128) {
    float s = 0.f;
    #pragma unroll 8
    for (int wp = 1; wp <= 56; ++wp) s += lds[wp * 133 + tid];
    rowsum[(size_t)blk * 128 + tid] = s;
  }
}

__global__ void attn_kernel(const float* __restrict__ rowsum, const float* __restrict__ aw1,
                            const float* __restrict__ aw2, const float* __restrict__ bias,
                            float* __restrict__ attn, float* __restrict__ bc_out) {
  int b = blockIdx.x;
  __shared__ float sp[NC], h1[NCR], at[NK];
  int t = threadIdx.x;
  if (t < NC) {
    float s = 0.f;
    for (int hp = 1; hp <= 56; ++hp) s += rowsum[((size_t)b * 58 + hp) * 128 + t];
    sp[t] = s * (1.0f / (float)NHW);
  }
  __syncthreads();
  if (t < NCR) {
    float s = 0.f;
    for (int c = 0; c < NC; ++c) s += aw1[t*NC + c] * sp[c];
    h1[t] = s > 0.f ? s : 0.f;
  }
  __syncthreads();
  if (t == 0) {
    float lg[NK], mx = -1e30f;
    for (int k = 0; k < NK; ++k) {
      float s = 0.f;
      for (int r = 0; r < NCR; ++r) s += aw2[k*NCR + r] * h1[r];
      lg[k] = s * (1.0f/TEMPER);
      mx = fmaxf(mx, lg[k]);
    }
    float den = 0.f, e[NK];
    for (int k = 0; k < NK; ++k) { e[k] = expf(lg[k]-mx); den += e[k]; }
    float inv = 1.0f/den;
    for (int k = 0; k < NK; ++k) { at[k] = e[k]*inv; attn[b*NK+k] = at[k]; }
  }
  __syncthreads();
  if (t < NCO) {
    float s = 0.f;
    for (int k = 0; k < NK; ++k) s += at[k] * bias[k*NCO + t];
    bc_out[b*NCO + t] = s;
  }
}

// combine (one-pass LDS-tiled): block g owns (co = g>>1, ci range (g&1)*64+0..63).
// Reads its W slice once into LDS (coalesced), writes wc for all 32 b's as
// u16x8 (128B runs per (b,j)). W total is 2.36 MB -> fully L2/L3 resident.
__global__ void combine_kernel(const float* __restrict__ W, const float* __restrict__ attn,
                               __hip_bfloat16* __restrict__ wc) {
  __shared__ float wlds[4*576];   // [k][ci(64)*9+j]
  __shared__ float alds[128];
  int g = blockIdx.x, tid = threadIdx.x;
  int co = g >> 1, cig0 = (g & 1) * 64;
  const float* wbase = W + (size_t)co*1152 + cig0*9;
  #pragma unroll
  for (int k = 0; k < 4; ++k)
    for (int i = tid; i < 576; i += 256)
      wlds[k*576 + i] = wbase[(size_t)k*147456 + i];
  if (tid < 128) alds[tid] = attn[tid];
  __syncthreads();
  int b  = tid >> 3;              // 0..31
  int c8 = (tid & 7) * 8;         // ci sub-base
  float a0 = alds[b*4+0], a1 = alds[b*4+1], a2 = alds[b*4+2], a3 = alds[b*4+3];
  #pragma unroll
  for (int j = 0; j < 9; ++j) {
    u16x8 o;
    #pragma unroll
    for (int q = 0; q < 8; ++q) {
      int idx = (c8 + q)*9 + j;
      float v = a0*wlds[idx] + a1*wlds[576+idx] + a2*wlds[1152+idx] + a3*wlds[1728+idx];
      union { __hip_bfloat16 b; unsigned short u; } cv;
      cv.b = __float2bfloat16(v);
      o[q] = cv.u;
    }
    *(u16x8*)((unsigned short*)wc + (((size_t)b*9 + j)*128 + co)*128 + cig0 + c8) = o;
  }
}

// ------------------------------ conv ------------------------------
// Fully pipelined 2-phase (T3-minimum): A (weights) double-buffered in 3-khw
// LDS slabs via DIRECT global_load_lds (linear [khwL][co][32] layout; af-read
// slot residue (li*4+kg)%8 is perfectly uniform -> conflict-free), staged one
// kh-step ahead. B (x) double-buffered per-cc, staged one cc ahead at kh==0.
// Every __syncthreads drains only loads issued a full phase earlier (~free).
// Inner loop: pure ds_read + MFMA. Block = 128co x 448pos, 8 waves, grid 224.
#define RS 2368            // B row stride in shorts (296 16B-slots, %8==0)
#define CS 40              // B col cell stride in shorts
#define BROWS 10
#define BBUF (BROWS*RS)    // 23,680 shorts
#define ABUF (3*128*32)    // 12,288 shorts

#define GLOAD16(src, dst) \
  __builtin_amdgcn_global_load_lds( \
    (const __attribute__((address_space(1))) unsigned int*)(src), \
    (__attribute__((address_space(3))) unsigned int*)(dst), 16, 0, 0)

__global__ __launch_bounds__(512, 2) void conv_kernel(
    const unsigned short* __restrict__ xt,
    const unsigned short* __restrict__ wc,
    const float* __restrict__ bc,
    float* __restrict__ out) {
  __shared__ __align__(16) unsigned short lds_b[2*BBUF];   // 94,720 B
  __shared__ __align__(16) unsigned short lds_a[2*ABUF];   // 49,152 B
  const int tid  = threadIdx.x;        // 0..511
  const int lane = tid & 63;
  const int wv   = tid >> 6;           // 0..7
  const int wm   = wv >> 2;            // co strip *64
  const int wn   = wv & 3;             // pos strip *112
  const int bid  = blockIdx.x;         // 224 = 8*28
  const int xcd  = bid & 7;
  const int jj   = bid >> 3;           // 0..27
  const int b    = xcd*4 + jj/7;
  const int r0   = (jj % 7) * 8;       // 8 out rows per block
  const int li   = lane & 15;
  const int kg   = lane >> 4;

  // B staging map: 10 rows x 296 slots = 2960 chunks; 6 iters x 512 threads
  int srcB[6];
  #pragma unroll
  for (int i = 0; i < 6; ++i) {
    int q = i*512 + tid;
    int r = q / 296;
    int sl = q - r*296;
    int col = sl / 5;
    int part = sl - col*5;
    srcB[i] = (q < 2960 && col < 58 && part < 4)
              ? ((r0 + r)*58 + col)*128 + part*8 : -1;
  }
  // A staging map: 3 khw x 128 co x 4 parts = 1536 chunks; 3 iters x 512 (exact)
  int srcA[3];
  #pragma unroll
  for (int i = 0; i < 3; ++i) {
    int c = i*512 + tid;
    int khwL = c >> 9;
    int co   = (c & 511) >> 2;
    int part = c & 3;
    srcA[i] = (khwL*128 + co)*128 + part*8;   // + kh*49152 + cc*32 at stage time
  }

  int xoff[7];
  #pragma unroll
  for (int f = 0; f < 7; ++f) {
    int pos = wn*112 + f*16 + li;          // 0..447
    int rB = pos / 56;
    int cB = pos - rB*56;
    xoff[f] = rB*RS + cB*CS + kg*8;
  }
  const int aRead = (wm*64 + li)*32 + kg*8;  // + mo*512 + khwL*4096

  const f32x4 vzero = {0.f, 0.f, 0.f, 0.f};
  f32x4 acc[4][7];
  #pragma unroll
  for (int mo = 0; mo < 4; ++mo)
    #pragma unroll
    for (int f = 0; f < 7; ++f) acc[mo][f] = vzero;

  const unsigned short* xtg = xt + (size_t)b*(58*58*128);
  const unsigned short* wcg = wc + (size_t)b*(9*128*128);

  #define STAGE_B(bufidx, cc) do { \
    unsigned short* dbase = lds_b + (bufidx)*BBUF + wv*512; \
    _Pragma("unroll") \
    for (int i = 0; i < 6; ++i) { \
      if (srcB[i] >= 0) \
        GLOAD16(xtg + srcB[i] + (cc)*32, dbase + i*4096); \
    } \
  } while (0)

  #define STAGE_A(bufidx, cc, kh) do { \
    unsigned short* dbase = lds_a + (bufidx)*ABUF + wv*512; \
    _Pragma("unroll") \
    for (int i = 0; i < 3; ++i) \
      GLOAD16(wcg + (kh)*49152 + srcA[i] + (cc)*32, dbase + i*4096); \
  } while (0)

  // prologue: stage B(cc=0) and A(cc=0,kh=0); single exposed drain
  STAGE_B(0, 0);
  STAGE_A(0, 0, 0);
  __syncthreads();

  int cura = 0, curb = 0;
  for (int cc = 0; cc < 4; ++cc) {
    for (int kh = 0; kh < 3; ++kh) {
      // stage next A slab (lands during this step's compute)
      if (kh < 2)      STAGE_A(cura ^ 1, cc, kh + 1);
      else if (cc < 3) STAGE_A(cura ^ 1, cc + 1, 0);
      // stage next B tile once per cc (lands during 3 kh-steps of compute)
      if (kh == 0 && cc < 3) STAGE_B(curb ^ 1, cc + 1);

      const unsigned short* pa = lds_a + cura*ABUF;
      const unsigned short* pb = lds_b + curb*BBUF;
      #pragma unroll
      for (int kwl = 0; kwl < 3; ++kwl) {
        bf16x8 af[4];
        #pragma unroll
        for (int mo = 0; mo < 4; ++mo)
          af[mo] = *(const bf16x8*)(pa + kwl*4096 + aRead + mo*512);
        const int koff = kh*RS + kwl*CS;
        bf16x8 bfr[7];
        #pragma unroll
        for (int f = 0; f < 7; ++f)
          bfr[f] = *(const bf16x8*)(pb + xoff[f] + koff);
        __builtin_amdgcn_s_setprio(1);
        #pragma unroll
        for (int mo = 0; mo < 4; ++mo)
          #pragma unroll
          for (int f = 0; f < 7; ++f)
            acc[mo][f] = __builtin_amdgcn_mfma_f32_16x16x32_bf16(af[mo], bfr[f], acc[mo][f], 0, 0, 0);
        __builtin_amdgcn_s_setprio(0);
      }
      __syncthreads();   // drains loads issued a full phase ago (~free)
      cura ^= 1;
    }
    curb ^= 1;
  }

  float* ob = out + (size_t)b*NCO*NHW;
  #pragma unroll
  for (int mo = 0; mo < 4; ++mo) {
    #pragma unroll
    for (int rg = 0; rg < 4; ++rg) {
      const int co = wm*64 + mo*16 + kg*4 + rg;
      const float bv = bc[b*NCO + co];
      float* orow = ob + (size_t)co*NHW;
      #pragma unroll
      for (int f = 0; f < 7; ++f) {
        int pos = wn*112 + f*16 + li;
        int rB = pos / 56;
        int cB = pos - rB*56;
        orow[(r0 + rB)*56 + cB] = acc[mo][f][rg] + bv;
      }
    }
  }
}

extern "C" void kernel_launch(void* const* d_in, const int* in_sizes, int n_in,
                              void* d_out, int out_size, void* d_ws, size_t ws_size,
                              hipStream_t stream) {
  const float* x   = (const float*)d_in[0];
  const float* W   = (const float*)d_in[1];
  const float* bia = (const float*)d_in[2];
  const float* aw1 = (const float*)d_in[3];
  const float* aw2 = (const float*)d_in[4];
  float* out = (float*)d_out;
  char* ws = (char*)d_ws;
  float* attn   = (float*)(ws + WS_ATTN);
  float* bcm    = (float*)(ws + WS_BC);
  float* rowsum = (float*)(ws + WS_ROWSUM);
  __hip_bfloat16* wc = (__hip_bfloat16*)(ws + WS_WC);
  __hip_bfloat16* xt = (__hip_bfloat16*)(ws + WS_XT);

  xt_kernel<<<NB*58, 256, 0, stream>>>(x, xt, rowsum);
  attn_kernel<<<NB, 128, 0, stream>>>(rowsum, aw1, aw2, bia, attn, bcm);
  combine_kernel<<<256, 256, 0, stream>>>(W, attn, wc);
  conv_kernel<<<224, 512, 0, stream>>>((const unsigned short*)xt,
                                       (const unsigned short*)wc, bcm, out);
}

// Round 10
// 66.846 us; speedup vs baseline: 1.1549x; 1.1549x over previous
//
#include <hip/hip_runtime.h>
#include <hip/hip_bf16.h>
#include <stdint.h>

typedef __bf16 bf16x8 __attribute__((ext_vector_type(8)));
typedef float  f32x4  __attribute__((ext_vector_type(4)));
typedef unsigned short u16x8 __attribute__((ext_vector_type(8)));

#define NB 32
#define NC 128
#define NH 56
#define NW 56
#define NK 4
#define NCO 128
#define NCR 32
#define NHW 3136
#define TEMPER 30.0f

// ws byte offsets
#define WS_ATTN   0u         // 512 B
#define WS_BC     4096u      // 16 KB
#define WS_ROWSUM 65536u     // f32 [32][58][128] = 950,272 B
#define WS_WC     1048576u   // bf16 [32][9][128][128] = 9,437,184 B
#define WS_XT     10485760u  // bf16 [32][58][58][128] = 27,557,888 B

// fp32 NCHW -> bf16 [b][hp=58][wp=58][c=128] with zero halo, via LDS transpose.
// XCD-aligned to conv's b-map. Emits rowsum (pool fused).
__global__ void xt_kernel(const float* __restrict__ x, __hip_bfloat16* __restrict__ xt,
                          float* __restrict__ rowsum) {
  __shared__ float lds[58 * 133];
  int xcd = blockIdx.x & 7;
  int j   = blockIdx.x >> 3;               // 0..231
  int b   = xcd * 4 + j / 58;
  int hp  = j % 58;
  int blk = b * 58 + hp;
  int h = hp - 1;
  bool hin = (h >= 0) && (h < NH);
  int tid = threadIdx.x;
  if (hin) {
    const float* xrow = x + ((size_t)b * NC) * NHW + (size_t)h * NW;
    for (int i = tid; i < 128 * 14; i += 256) {
      int c = i / 14;
      int w4 = (i - c * 14) * 4;
      float4 v = *(const float4*)(xrow + (size_t)c * NHW + w4);
      int base = (w4 + 1) * 133 + c;
      lds[base]         = v.x;
      lds[base + 133]   = v.y;
      lds[base + 2*133] = v.z;
      lds[base + 3*133] = v.w;
    }
  }
  __syncthreads();
  __hip_bfloat16* orow = xt + (size_t)blk * (58 * 128);
  for (int i = tid; i < 58 * 16; i += 256) {
    int wp = i >> 4;
    int cg = (i & 15) << 3;
    u16x8 o;
    if (!hin || wp == 0 || wp == 57) {
      o = (u16x8)0;
    } else {
      const float* src = lds + wp * 133 + cg;
      #pragma unroll
      for (int jx = 0; jx < 8; ++jx) {
        union { __hip_bfloat16 b; unsigned short u; } cv;
        cv.b = __float2bfloat16(src[jx]);
        o[jx] = cv.u;
      }
    }
    *(u16x8*)(orow + wp * 128 + cg) = o;
  }
  if (hin && tid < 128) {
    float s = 0.f;
    #pragma unroll 8
    for (int wp = 1; wp <= 56; ++wp) s += lds[wp * 133 + tid];
    rowsum[(size_t)blk * 128 + tid] = s;
  }
}

__global__ void attn_kernel(const float* __restrict__ rowsum, const float* __restrict__ aw1,
                            const float* __restrict__ aw2, const float* __restrict__ bias,
                            float* __restrict__ attn, float* __restrict__ bc_out) {
  int b = blockIdx.x;
  __shared__ float sp[NC], h1[NCR], at[NK];
  int t = threadIdx.x;
  if (t < NC) {
    float s = 0.f;
    for (int hp = 1; hp <= 56; ++hp) s += rowsum[((size_t)b * 58 + hp) * 128 + t];
    sp[t] = s * (1.0f / (float)NHW);
  }
  __syncthreads();
  if (t < NCR) {
    float s = 0.f;
    for (int c = 0; c < NC; ++c) s += aw1[t*NC + c] * sp[c];
    h1[t] = s > 0.f ? s : 0.f;
  }
  __syncthreads();
  if (t == 0) {
    float lg[NK], mx = -1e30f;
    for (int k = 0; k < NK; ++k) {
      float s = 0.f;
      for (int r = 0; r < NCR; ++r) s += aw2[k*NCR + r] * h1[r];
      lg[k] = s * (1.0f/TEMPER);
      mx = fmaxf(mx, lg[k]);
    }
    float den = 0.f, e[NK];
    for (int k = 0; k < NK; ++k) { e[k] = expf(lg[k]-mx); den += e[k]; }
    float inv = 1.0f/den;
    for (int k = 0; k < NK; ++k) { at[k] = e[k]*inv; attn[b*NK+k] = at[k]; }
  }
  __syncthreads();
  if (t < NCO) {
    float s = 0.f;
    for (int k = 0; k < NK; ++k) s += at[k] * bias[k*NCO + t];
    bc_out[b*NCO + t] = s;
  }
}

// combine (R7 version, known-good in the 66.4us run)
__global__ void combine_kernel(const float* __restrict__ W, const float* __restrict__ attn,
                               __hip_bfloat16* __restrict__ wc) {
  int gid = blockIdx.x;                     // 256 blocks
  int bg  = gid >> 6;
  int tcell = (gid & 63) * 256 + threadIdx.x;
  int co = tcell >> 7, ci = tcell & 127;
  float w[4][9];
  const float* wp = W + ((size_t)co * 128 + ci) * 9;
  #pragma unroll
  for (int k = 0; k < 4; ++k)
    #pragma unroll
    for (int j = 0; j < 9; ++j)
      w[k][j] = wp[(size_t)k * 147456 + j];
  for (int b = bg * 8; b < bg * 8 + 8; ++b) {
    float a0 = attn[b*4+0], a1 = attn[b*4+1], a2 = attn[b*4+2], a3 = attn[b*4+3];
    #pragma unroll
    for (int j = 0; j < 9; ++j) {
      float v = a0*w[0][j] + a1*w[1][j] + a2*w[2][j] + a3*w[3][j];
      wc[(((size_t)b*9 + j) * 128 + co) * 128 + ci] = __float2bfloat16(v);
    }
  }
}

// ------------------------------ conv ------------------------------
// Single long compute phase per cc (2 barriers/cc, 8 total):
//   [readers-done barrier] -> stage A(9 khw, linear gload_lds) + B -> [drain
//   barrier] -> 9 MFMA-groups with REGISTER PING-PONG ds_read pipelining
//   (group g+1's 11 ds_read_b128 issued before group g's 28 MFMAs -> counted
//   lgkmcnt, LDS pipe runs concurrently with matrix pipe).
// Block = 128co x 448pos (8 out rows), 8 waves (wave 64co x 112pos), grid 224.
#define RS 2368            // B row stride in shorts (296 16B-slots, %8==0)
#define CS 40              // B col cell stride in shorts
#define BBUF (10*RS)       // 23,680 shorts = 47,360 B
#define ABUF (9*128*32)    // 36,864 shorts = 73,728 B

#define GLOAD16(src, dst) \
  __builtin_amdgcn_global_load_lds( \
    (const __attribute__((address_space(1))) unsigned int*)(src), \
    (__attribute__((address_space(3))) unsigned int*)(dst), 16, 0, 0)

__global__ __launch_bounds__(512, 2) void conv_kernel(
    const unsigned short* __restrict__ xt,
    const unsigned short* __restrict__ wc,
    const float* __restrict__ bc,
    float* __restrict__ out) {
  __shared__ __align__(16) unsigned short lds_a[ABUF];   // 73,728 B
  __shared__ __align__(16) unsigned short lds_b[BBUF];   // 47,360 B
  const int tid  = threadIdx.x;        // 0..511
  const int lane = tid & 63;
  const int wv   = tid >> 6;           // 0..7
  const int wm   = wv >> 2;            // co strip *64
  const int wn   = wv & 3;             // pos strip *112
  const int bid  = blockIdx.x;         // 224 = 8*28
  const int xcd  = bid & 7;
  const int jj   = bid >> 3;           // 0..27
  const int b    = xcd*4 + jj/7;
  const int r0   = (jj % 7) * 8;       // 8 out rows per block
  const int li   = lane & 15;
  const int kg   = lane >> 4;

  // B staging map: 10 rows x 296 slots = 2960 chunks; 6 iters x 512 threads
  int srcB[6];
  #pragma unroll
  for (int i = 0; i < 6; ++i) {
    int q = i*512 + tid;
    int r = q / 296;
    int sl = q - r*296;
    int col = sl / 5;
    int part = sl - col*5;
    srcB[i] = (q < 2960 && col < 58 && part < 4)
              ? ((r0 + r)*58 + col)*128 + part*8 : -1;
  }
  // A staging map: 9 khw x 128 co x 4 parts = 4608 chunks; 9 iters x 512 (exact)
  // dest is LINEAR (chunk c -> lds_a + c*8 shorts) == [khw][co][32] layout.
  int srcA[9];
  #pragma unroll
  for (int i = 0; i < 9; ++i) {
    int c = i*512 + tid;
    int khw  = c >> 9;
    int co   = (c & 511) >> 2;
    int part = c & 3;
    srcA[i] = (khw*128 + co)*128 + part*8;   // + cc*32 at stage time
  }

  int xoff[7];
  #pragma unroll
  for (int f = 0; f < 7; ++f) {
    int pos = wn*112 + f*16 + li;          // 0..447
    int rB = pos / 56;
    int cB = pos - rB*56;
    xoff[f] = rB*RS + cB*CS + kg*8;
  }
  const int aRead = (wm*64 + li)*32 + kg*8;  // + mo*512 + khw*4096

  const f32x4 vzero = {0.f, 0.f, 0.f, 0.f};
  f32x4 acc[4][7];
  #pragma unroll
  for (int mo = 0; mo < 4; ++mo)
    #pragma unroll
    for (int f = 0; f < 7; ++f) acc[mo][f] = vzero;

  const unsigned short* xtg = xt + (size_t)b*(58*58*128);
  const unsigned short* wcg = wc + (size_t)b*(9*128*128);

  // frag load / mfma helpers on named sets (static indexing, rule #20)
  #define LOADFRAG(AF, BF, khw) do { \
    const int kh_ = (khw)/3, kw_ = (khw)-kh_*3; \
    _Pragma("unroll") \
    for (int mo = 0; mo < 4; ++mo) \
      AF[mo] = *(const bf16x8*)(lds_a + (khw)*4096 + aRead + mo*512); \
    const int koff_ = kh_*RS + kw_*CS; \
    _Pragma("unroll") \
    for (int f = 0; f < 7; ++f) \
      BF[f] = *(const bf16x8*)(lds_b + xoff[f] + koff_); \
  } while (0)

  #define DOMFMA(AF, BF) do { \
    _Pragma("unroll") \
    for (int mo = 0; mo < 4; ++mo) \
      _Pragma("unroll") \
      for (int f = 0; f < 7; ++f) \
        acc[mo][f] = __builtin_amdgcn_mfma_f32_16x16x32_bf16(AF[mo], BF[f], acc[mo][f], 0, 0, 0); \
  } while (0)

  for (int cc = 0; cc < 4; ++cc) {
    if (cc > 0) __syncthreads();     // all readers of previous cc done
    // stage A (9 gloads) + B (<=6 gloads) into single buffers
    #pragma unroll
    for (int i = 0; i < 9; ++i)
      GLOAD16(wcg + srcA[i] + cc*32, lds_a + (i*512 + wv*64)*8);
    #pragma unroll
    for (int i = 0; i < 6; ++i)
      if (srcB[i] >= 0)
        GLOAD16(xtg + srcB[i] + cc*32, lds_b + (i*512 + wv*64)*8);
    __syncthreads();                 // vmcnt(0) drain: tiles ready

    bf16x8 afE[4], bfE[7], afO[4], bfO[7];
    LOADFRAG(afE, bfE, 0);
    LOADFRAG(afO, bfO, 1);
    DOMFMA(afE, bfE);                // g0 (overlaps g1 loads in flight)
    LOADFRAG(afE, bfE, 2);
    DOMFMA(afO, bfO);                // g1
    LOADFRAG(afO, bfO, 3);
    DOMFMA(afE, bfE);                // g2
    LOADFRAG(afE, bfE, 4);
    DOMFMA(afO, bfO);                // g3
    LOADFRAG(afO, bfO, 5);
    DOMFMA(afE, bfE);                // g4
    LOADFRAG(afE, bfE, 6);
    DOMFMA(afO, bfO);                // g5
    LOADFRAG(afO, bfO, 7);
    DOMFMA(afE, bfE);                // g6
    LOADFRAG(afE, bfE, 8);
    DOMFMA(afO, bfO);                // g7
    DOMFMA(afE, bfE);                // g8
  }

  float* ob = out + (size_t)b*NCO*NHW;
  #pragma unroll
  for (int mo = 0; mo < 4; ++mo) {
    #pragma unroll
    for (int rg = 0; rg < 4; ++rg) {
      const int co = wm*64 + mo*16 + kg*4 + rg;
      const float bv = bc[b*NCO + co];
      float* orow = ob + (size_t)co*NHW;
      #pragma unroll
      for (int f = 0; f < 7; ++f) {
        int pos = wn*112 + f*16 + li;
        int rB = pos / 56;
        int cB = pos - rB*56;
        orow[(r0 + rB)*56 + cB] = acc[mo][f][rg] + bv;
      }
    }
  }
}

extern "C" void kernel_launch(void* const* d_in, const int* in_sizes, int n_in,
                              void* d_out, int out_size, void* d_ws, size_t ws_size,
                              hipStream_t stream) {
  const float* x   = (const float*)d_in[0];
  const float* W   = (const float*)d_in[1];
  const float* bia = (const float*)d_in[2];
  const float* aw1 = (const float*)d_in[3];
  const float* aw2 = (const float*)d_in[4];
  float* out = (float*)d_out;
  char* ws = (char*)d_ws;
  float* attn   = (float*)(ws + WS_ATTN);
  float* bcm    = (float*)(ws + WS_BC);
  float* rowsum = (float*)(ws + WS_ROWSUM);
  __hip_bfloat16* wc = (__hip_bfloat16*)(ws + WS_WC);
  __hip_bfloat16* xt = (__hip_bfloat16*)(ws + WS_XT);

  xt_kernel<<<NB*58, 256, 0, stream>>>(x, xt, rowsum);
  attn_kernel<<<NB, 128, 0, stream>>>(rowsum, aw1, aw2, bia, attn, bcm);
  combine_kernel<<<256, 256, 0, stream>>>(W, attn, wc);
  conv_kernel<<<224, 512, 0, stream>>>((const unsigned short*)xt,
                                       (const unsigned short*)wc, bcm, out);
}